// Round 5
// baseline (150.430 us; speedup 1.0000x reference)
//
#include <hip/hip_runtime.h>
#include <hip/hip_bf16.h>
#include <math.h>

#define B_   32
#define J_   1182      // V*P = 6*197
#define D_   512
#define L_   77
#define C_   5
#define JC_  64
#define NCH_ 19        // ceil(1182/64)

__device__ __forceinline__ float dot4(float4 a, float4 b) {
    return a.x*b.x + a.y*b.y + a.z*b.z + a.w*b.w;
}

__device__ __forceinline__ float wave_sum(float v) {
#pragma unroll
    for (int off = 32; off > 0; off >>= 1) v += __shfl_xor(v, off, 64);
    return v;
}

__device__ __forceinline__ float wave_max(float v) {
#pragma unroll
    for (int off = 32; off > 0; off >>= 1) v = fmaxf(v, __shfl_xor(v, off, 64));
    return v;
}

// K1: blocks 0..1371: cond_maps (o-major, wave per o, 5 conditions per weight read)
//     block 1372: fn normalize (LDS) + loss_dis -> loss_out
__global__ void k_setup(const float* __restrict__ fc, const float* __restrict__ cw,
                        const float* __restrict__ cb, float* __restrict__ cm,
                        float* __restrict__ loss_out) {
    __shared__ float sfc[C_*D_];
    int t = threadIdx.x;
    for (int i = t; i < C_*D_; i += 256) sfc[i] = fc[i];
    __syncthreads();
    int wave = t >> 6, lane = t & 63;

    if (blockIdx.x == 1372) {
        // normalize each condition row in LDS (wave per c)
        for (int c = wave; c < C_; c += 4) {
            float ss = 0.f;
            for (int d = lane; d < D_; d += 64) { float v = sfc[c*D_+d]; ss += v*v; }
            ss = wave_sum(ss);
            float inv = 1.f / fmaxf(sqrtf(ss), 1e-12f);
            for (int d = lane; d < D_; d += 64) sfc[c*D_+d] *= inv;
        }
        __syncthreads();
        if (wave == 0) {
            float acc = 0.f;
            for (int i = 0; i < C_; ++i)
                for (int j = i+1; j < C_; ++j) {
                    float p = 0.f;
                    for (int d = lane; d < D_; d += 64) p += sfc[i*D_+d]*sfc[j*D_+d];
                    p = wave_sum(p);
                    acc += fmaxf(p, 0.f);
                }
            if (lane == 0) *loss_out = acc * (1.f/10.f);
        }
        return;
    }

    int o = blockIdx.x*4 + wave;         // < 5488
    const float4* w4 = (const float4*)(cw + (size_t)o*D_);
    float4 wa = w4[lane], wb = w4[lane+64];
    float bias = cb[o];
    float keep = 0.f;
#pragma unroll
    for (int c = 0; c < C_; ++c) {
        const float4* f4 = (const float4*)(sfc + c*D_);
        float s = dot4(wa, f4[lane]) + dot4(wb, f4[lane+64]);
        s = wave_sum(s);
        if (lane == c) keep = s;
    }
    if (lane < C_) cm[lane*5488 + o] = keep + bias;
}

// K2: fused prompt path per b: fn (redundant, in LDS) -> row norms + sim_cond -> Q.
// No npb / sc globals.
__global__ void k_prompt(const float* __restrict__ fp, const float* __restrict__ fcond,
                         float* __restrict__ Q) {
    __shared__ float sfn[C_*D_];         // normalized conditions
    __shared__ float swl[C_][80];        // sc[c][l] * inv_l^2  (combined weight)
    int b = blockIdx.x, t = threadIdx.x, wave = t >> 6, lane = t & 63;

    for (int i = t; i < C_*D_; i += 256) sfn[i] = fcond[i];
    __syncthreads();
    for (int c = wave; c < C_; c += 4) {
        float ss = 0.f;
        for (int d = lane; d < D_; d += 64) { float v = sfn[c*D_+d]; ss += v*v; }
        ss = wave_sum(ss);
        float inv = 1.f / fmaxf(sqrtf(ss), 1e-12f);
        for (int d = lane; d < D_; d += 64) sfn[c*D_+d] *= inv;
    }
    __syncthreads();

    // per-row: norm + 5 condition dots
    for (int l = wave; l < L_; l += 4) {
        const float4* p = (const float4*)(fp + ((size_t)(b*L_ + l))*D_);
        float4 a = p[lane], a2 = p[lane+64];
        float ss = wave_sum(dot4(a,a) + dot4(a2,a2));
        float inv = 1.f / fmaxf(sqrtf(ss), 1e-12f);
        float inv2 = inv*inv;
#pragma unroll
        for (int c = 0; c < C_; ++c) {
            const float4* q4 = (const float4*)(sfn + c*D_);
            float s = dot4(a, q4[lane]) + dot4(a2, q4[lane+64]);
            s = wave_sum(s);
            if (lane == c) swl[c][l] = s * inv2;
        }
    }
    __syncthreads();

    // Q[c,d] = sum_l swl[c][l] * fp[b,l,d]   (fp re-read, L2-hot)
    float2 a0={0,0}, a1={0,0}, a2={0,0}, a3={0,0}, a4={0,0};
    const float2* f2 = (const float2*)(fp + (size_t)b*L_*D_) + t;
    for (int l = 0; l < L_; ++l) {
        float2 v = f2[(size_t)l*256];
        float w0=swl[0][l], w1=swl[1][l], w2=swl[2][l], w3=swl[3][l], w4=swl[4][l];
        a0.x += w0*v.x; a0.y += w0*v.y;
        a1.x += w1*v.x; a1.y += w1*v.y;
        a2.x += w2*v.x; a2.y += w2*v.y;
        a3.x += w3*v.x; a3.y += w3*v.y;
        a4.x += w4*v.x; a4.y += w4*v.y;
    }
    ((float2*)(Q + (size_t)(b*C_+0)*D_))[t] = a0;
    ((float2*)(Q + (size_t)(b*C_+1)*D_))[t] = a1;
    ((float2*)(Q + (size_t)(b*C_+2)*D_))[t] = a2;
    ((float2*)(Q + (size_t)(b*C_+3)*D_))[t] = a3;
    ((float2*)(Q + (size_t)(b*C_+4)*D_))[t] = a4;
}

// K3: pw_raw[b,c,j] = (1/||tex[b,j]||) * dot(tex[b,j,:], Q[b,c,:])  [tex stream #1]
// 4 j per block (wave per j), Q staged in LDS.
__global__ void k_pw(const float* __restrict__ tex, const float* __restrict__ Q,
                     float* __restrict__ pw) {
    __shared__ float sq[C_*D_];
    int b = blockIdx.y, t = threadIdx.x;
    for (int i = t; i < C_*D_; i += 256) sq[i] = Q[(size_t)b*C_*D_ + i];
    __syncthreads();
    int wave = t >> 6, lane = t & 63;
    int j = blockIdx.x*4 + wave;
    if (j >= J_) return;
    const float4* t4 = (const float4*)(tex + ((size_t)b*J_ + j)*D_);
    float4 a = t4[lane], a2 = t4[lane+64];
    float ss = wave_sum(dot4(a,a) + dot4(a2,a2));
    float inv = 1.f / fmaxf(sqrtf(ss), 1e-12f);
    float keep = 0.f;
#pragma unroll
    for (int c = 0; c < C_; ++c) {
        const float4* q4 = (const float4*)(sq + c*D_);
        float s = dot4(a, q4[lane]) + dot4(a2, q4[lane+64]);
        s = wave_sum(s);
        if (lane == c) keep = s * inv;
    }
    if (lane < C_) pw[((size_t)(b*C_+lane))*J_ + j] = keep;
}

// K4: ftf partials with inline softmax  [tex stream #2]
// pre-phase: waves 0..4 compute (m, 1/sum) for row (b,wave) redundantly per block;
// main: sw[c][jj] = exp(raw-m)*inv; accumulate over chunk.
__global__ void k_ftf(const float* __restrict__ tex, const float* __restrict__ pwraw,
                      float* __restrict__ part) {
    __shared__ float sw[C_][JC_];
    __shared__ float sms[C_][2];
    int chunk = blockIdx.x, b = blockIdx.y;
    int t = threadIdx.x;                 // 512
    int wave = t >> 6, lane = t & 63;
    if (wave < C_) {
        const float* row = pwraw + (size_t)(b*C_+wave)*J_;
        float m = -1e30f;
        for (int j = lane; j < J_; j += 64) m = fmaxf(m, row[j]);
        m = wave_max(m);
        float s = 0.f;
        for (int j = lane; j < J_; j += 64) s += expf(row[j] - m);
        s = wave_sum(s);
        if (lane == 0) { sms[wave][0] = m; sms[wave][1] = 1.f/s; }
    }
    __syncthreads();
    int j0 = chunk*JC_;
    int jn = min(JC_, J_ - j0);
    if (t < C_*JC_) {
        int c = t >> 6, jj = t & 63;
        sw[c][jj] = (jj < jn)
            ? expf(pwraw[((size_t)(b*C_+c))*J_ + j0 + jj] - sms[c][0]) * sms[c][1]
            : 0.f;
    }
    __syncthreads();
    float acc0=0.f, acc1=0.f, acc2=0.f, acc3=0.f, acc4=0.f;
    const float* tp = tex + ((size_t)b*J_ + j0)*D_ + t;
    for (int jj = 0; jj < jn; ++jj) {
        float v = tp[(size_t)jj*D_];
        acc0 += v*sw[0][jj]; acc1 += v*sw[1][jj]; acc2 += v*sw[2][jj];
        acc3 += v*sw[3][jj]; acc4 += v*sw[4][jj];
    }
    size_t base = (((size_t)chunk*B_ + b)*C_)*D_ + t;
    part[base               ] = acc0;
    part[base +   (size_t)D_] = acc1;
    part[base + 2*(size_t)D_] = acc2;
    part[base + 3*(size_t)D_] = acc3;
    part[base + 4*(size_t)D_] = acc4;
}

// K5: fused fq + TargetNet per (b,c) block. No shuffles anywhere.
__global__ void k_fq_target(const float* __restrict__ part, const float* __restrict__ eot,
                            const float* __restrict__ qw, const float* __restrict__ qb,
                            const float* __restrict__ g1w, const float* __restrict__ g2w,
                            const float* __restrict__ g3w, const float* __restrict__ g4w,
                            const float* __restrict__ fcb, float* __restrict__ out) {
    int bc = blockIdx.x; int b = bc / C_; int c = bc - b*C_;
    __shared__ float sf[D_];
    __shared__ float sa[224], sb[112];
    int t = threadIdx.x;                 // 256

    float s0 = 0.f, s1 = 0.f;
    for (int ch = 0; ch < NCH_; ++ch) {
        const float* p = part + ((size_t)ch*(B_*C_) + bc)*D_;
        s0 += p[t]; s1 += p[t+256];
    }
    sf[t]     = s0 * eot[b*D_ + t];
    sf[t+256] = s1 * eot[b*D_ + t + 256];
    __syncthreads();

    if (t < 224) {
        const float4* w4 = (const float4*)(qw + (size_t)t*D_);
        const float4* s4 = (const float4*)sf;
        float acc = 0.f;
#pragma unroll 4
        for (int i = 0; i < 128; ++i) acc += dot4(s4[i], w4[i]);
        sa[t] = acc + qb[t];
    }
    __syncthreads();

    if (t < 112) {
        const float* w = g1w + (size_t)c*25088 + t*224;
        float s = fcb[c*112 + t];
        for (int k = 0; k < 224; ++k) s += w[k]*sa[k];
        sb[t] = 1.f/(1.f+expf(-s));
    }
    __syncthreads();
    if (t < 56) {
        const float* w = g2w + (size_t)c*6272 + t*112;
        float s = fcb[560 + c*56 + t];
        for (int k = 0; k < 112; ++k) s += w[k]*sb[k];
        sa[t] = 1.f/(1.f+expf(-s));
    }
    __syncthreads();
    if (t < 28) {
        const float* w = g3w + (size_t)c*1568 + t*56;
        float s = fcb[840 + c*28 + t];
        for (int k = 0; k < 56; ++k) s += w[k]*sa[k];
        sb[t] = 1.f/(1.f+expf(-s));
    }
    __syncthreads();
    if (t < 14) {
        const float* w = g4w + (size_t)c*392 + t*28;
        float s = fcb[980 + c*14 + t];
        for (int k = 0; k < 28; ++k) s += w[k]*sb[k];
        sa[t] = 1.f/(1.f+expf(-s));
    }
    __syncthreads();
    if (t == 0) {
        float s = fcb[1120 + c];
        for (int p = 0; p < 14; ++p) s += sa[p]*fcb[1050 + c*14 + p];
        out[b*C_ + c] = s;
    }
}

// K6: convs + (on blockIdx.x==0) pooled + hypernet fc biases.
// Thread = (o_comb, row y, channel-quarter chq); 7 x-outputs each; LDS image
// padded [112][9][12]. fcb layout: [0,560) fc1b | [560,840) fc2b | [840,980) fc3b
// | [980,1050) fc4b | [1050,1120) fc5w | [1120,1125) fc5b
__global__ void k_conv(const float* __restrict__ cm,
                       const float* __restrict__ w1, const float* __restrict__ bb1,
                       const float* __restrict__ w2, const float* __restrict__ bb2,
                       const float* __restrict__ w3, const float* __restrict__ bb3,
                       const float* __restrict__ w4, const float* __restrict__ bb4,
                       float* __restrict__ o1, float* __restrict__ o2,
                       float* __restrict__ o3, float* __restrict__ o4,
                       const float* __restrict__ w1b, const float* __restrict__ b1b,
                       const float* __restrict__ w2b, const float* __restrict__ b2b,
                       const float* __restrict__ w3b, const float* __restrict__ b3b,
                       const float* __restrict__ w4b, const float* __restrict__ b4b,
                       const float* __restrict__ w5w, const float* __restrict__ b5w,
                       const float* __restrict__ w5b, const float* __restrict__ b5b,
                       float* __restrict__ fcb) {
    __shared__ float im[112*108];
    __shared__ float sp[112];
    int c = blockIdx.y;
    int t = threadIdx.x;
    for (int i = t; i < 112*108; i += 256) im[i] = 0.f;
    __syncthreads();
    const float* cmc = cm + c*5488;
    for (int i = t; i < 112*49; i += 256) {
        int ch = i / 49, yx = i - ch*49;
        int y = yx / 7, x = yx - y*7;
        im[ch*108 + (y+1)*12 + (x+1)] = cmc[i];
    }
    __syncthreads();

    int oy  = blockIdx.x*64 + (t >> 2);
    int chq = t & 3;
    if (oy < 4760) {
        int o_comb = oy / 7, y = oy - o_comb*7;
        const float* w; const float* bias; float* outp; int o;
        if      (o_comb < 512) { w=w1; bias=bb1; outp=o1 + (size_t)c*512*49; o=o_comb; }
        else if (o_comb < 640) { w=w2; bias=bb2; outp=o2 + (size_t)c*128*49; o=o_comb-512; }
        else if (o_comb < 672) { w=w3; bias=bb3; outp=o3 + (size_t)c*32*49;  o=o_comb-640; }
        else                   { w=w4; bias=bb4; outp=o4 + (size_t)c*8*49;   o=o_comb-672; }

        float ac0=0,ac1=0,ac2=0,ac3=0,ac4=0,ac5=0,ac6=0;
        const float* wbase = w + ((size_t)o*112 + chq*28)*9;
        const float* imc   = im + (chq*28)*108 + y*12;
#pragma unroll 2
        for (int ch = 0; ch < 28; ++ch) {
            const float* wk = wbase + ch*9;
            const float* ii = imc + ch*108;
            float w0=wk[0],w1_=wk[1],w2_=wk[2],w3_=wk[3],w4_=wk[4],w5_=wk[5],w6_=wk[6],w7_=wk[7],w8_=wk[8];
#pragma unroll
            for (int ky = 0; ky < 3; ++ky) {
                const float* row = ii + ky*12;
                float4 ra = *(const float4*)(row);
                float4 rb = *(const float4*)(row + 4);
                float  rc = row[8];
                float r0=ra.x,r1=ra.y,r2=ra.z,r3=ra.w,r4=rb.x,r5=rb.y,r6=rb.z,r7=rb.w,r8=rc;
                float wk0 = (ky==0)?w0:((ky==1)?w3_:w6_);
                float wk1 = (ky==0)?w1_:((ky==1)?w4_:w7_);
                float wk2 = (ky==0)?w2_:((ky==1)?w5_:w8_);
                ac0 += r0*wk0 + r1*wk1 + r2*wk2;
                ac1 += r1*wk0 + r2*wk1 + r3*wk2;
                ac2 += r2*wk0 + r3*wk1 + r4*wk2;
                ac3 += r3*wk0 + r4*wk1 + r5*wk2;
                ac4 += r4*wk0 + r5*wk1 + r6*wk2;
                ac5 += r5*wk0 + r6*wk1 + r7*wk2;
                ac6 += r6*wk0 + r7*wk1 + r8*wk2;
            }
        }
        ac0 += __shfl_xor(ac0,1,64); ac0 += __shfl_xor(ac0,2,64);
        ac1 += __shfl_xor(ac1,1,64); ac1 += __shfl_xor(ac1,2,64);
        ac2 += __shfl_xor(ac2,1,64); ac2 += __shfl_xor(ac2,2,64);
        ac3 += __shfl_xor(ac3,1,64); ac3 += __shfl_xor(ac3,2,64);
        ac4 += __shfl_xor(ac4,1,64); ac4 += __shfl_xor(ac4,2,64);
        ac5 += __shfl_xor(ac5,1,64); ac5 += __shfl_xor(ac5,2,64);
        ac6 += __shfl_xor(ac6,1,64); ac6 += __shfl_xor(ac6,2,64);
        if (chq == 0) {
            float bo = bias[o];
            float* dst = outp + o*49 + y*7;
            dst[0]=ac0+bo; dst[1]=ac1+bo; dst[2]=ac2+bo; dst[3]=ac3+bo;
            dst[4]=ac4+bo; dst[5]=ac5+bo; dst[6]=ac6+bo;
        }
    }

    // hypernet biases on block (0, c); padded zeros don't affect the 7x7 sum
    if (blockIdx.x == 0) {
        if (t < 112) {
            const float* p = im + t*108;
            float s = 0.f;
            for (int k = 0; k < 108; ++k) s += p[k];
            sp[t] = s * (1.f/49.f);
        }
        __syncthreads();
        if (t < 225) {
            int rel = t;
            const float* w; const float* bb; int nout; int base;
            if      (rel < 112) {            w=w1b; bb=b1b; nout=112; base=0; }
            else if (rel < 168) { rel-=112;  w=w2b; bb=b2b; nout=56;  base=560; }
            else if (rel < 196) { rel-=168;  w=w3b; bb=b3b; nout=28;  base=840; }
            else if (rel < 210) { rel-=196;  w=w4b; bb=b4b; nout=14;  base=980; }
            else if (rel < 224) { rel-=210;  w=w5w; bb=b5w; nout=14;  base=1050; }
            else                { rel-=224;  w=w5b; bb=b5b; nout=1;   base=1120; }
            float s = bb[rel];
            const float* wr = w + rel*112;
            for (int i = 0; i < 112; ++i) s += sp[i]*wr[i];
            fcb[base + c*nout + rel] = s;
        }
    }
}

extern "C" void kernel_launch(void* const* d_in, const int* in_sizes, int n_in,
                              void* d_out, int out_size, void* d_ws, size_t ws_size,
                              hipStream_t stream) {
    (void)in_sizes; (void)n_in; (void)out_size; (void)ws_size;
    const float* tex   = (const float*)d_in[0];
    const float* fp    = (const float*)d_in[1];
    const float* eot   = (const float*)d_in[2];
    const float* fcond = (const float*)d_in[3];
    const float* qw    = (const float*)d_in[4];
    const float* qb    = (const float*)d_in[5];
    const float* cw    = (const float*)d_in[6];
    const float* cb    = (const float*)d_in[7];
    const float* w1c   = (const float*)d_in[8];  const float* b1c = (const float*)d_in[9];
    const float* w2c   = (const float*)d_in[10]; const float* b2c = (const float*)d_in[11];
    const float* w3c   = (const float*)d_in[12]; const float* b3c = (const float*)d_in[13];
    const float* w4c   = (const float*)d_in[14]; const float* b4c = (const float*)d_in[15];
    const float* f1bw  = (const float*)d_in[16]; const float* f1bb = (const float*)d_in[17];
    const float* f2bw  = (const float*)d_in[18]; const float* f2bb = (const float*)d_in[19];
    const float* f3bw  = (const float*)d_in[20]; const float* f3bb = (const float*)d_in[21];
    const float* f4bw  = (const float*)d_in[22]; const float* f4bb = (const float*)d_in[23];
    const float* f5ww  = (const float*)d_in[24]; const float* f5wb = (const float*)d_in[25];
    const float* f5bw  = (const float*)d_in[26]; const float* f5bb = (const float*)d_in[27];
    float* out = (float*)d_out;

    float* ws     = (float*)d_ws;
    float* Qb     = ws;                         // 81920
    float* pw     = Qb + 81920;                 // 189120
    float* part   = pw + 189120;                // NCH*81920
    float* cm     = part + (size_t)NCH_*81920;  // 27440
    float* g1w    = cm + 27440;                 // 125440
    float* g2w    = g1w + 125440;               // 31360
    float* g3w    = g2w + 31360;                // 7840
    float* g4w    = g3w + 7840;                 // 1960
    float* fcb    = g4w + 1960;                 // 1125

    k_setup<<<1373, 256, 0, stream>>>(fcond, cw, cb, cm, out + B_*C_);
    k_prompt<<<B_, 256, 0, stream>>>(fp, fcond, Qb);
    k_conv<<<dim3(75, C_), 256, 0, stream>>>(cm, w1c, b1c, w2c, b2c, w3c, b3c, w4c, b4c,
                                             g1w, g2w, g3w, g4w,
                                             f1bw, f1bb, f2bw, f2bb, f3bw, f3bb,
                                             f4bw, f4bb, f5ww, f5wb, f5bw, f5bb, fcb);
    k_pw<<<dim3(296, B_), 256, 0, stream>>>(tex, Qb, pw);
    k_ftf<<<dim3(NCH_, B_), 512, 0, stream>>>(tex, pw, part);
    k_fq_target<<<B_*C_, 256, 0, stream>>>(part, eot, qw, qb,
                                           g1w, g2w, g3w, g4w, fcb, out);
}

// Round 6
// 125.493 us; speedup vs baseline: 1.1987x; 1.1987x over previous
//
#include <hip/hip_runtime.h>
#include <hip/hip_bf16.h>
#include <math.h>

#define B_   32
#define J_   1182      // V*P = 6*197
#define D_   512
#define L_   77
#define C_   5
#define JC_  64
#define NCH_ 19        // ceil(1182/64)

__device__ __forceinline__ float dot4(float4 a, float4 b) {
    return a.x*b.x + a.y*b.y + a.z*b.z + a.w*b.w;
}

__device__ __forceinline__ float wave_sum(float v) {
#pragma unroll
    for (int off = 32; off > 0; off >>= 1) v += __shfl_xor(v, off, 64);
    return v;
}

__device__ __forceinline__ float wave_max(float v) {
#pragma unroll
    for (int off = 32; off > 0; off >>= 1) v = fmaxf(v, __shfl_xor(v, off, 64));
    return v;
}

// K1: blocks 0..1371: cond_maps (o-major, wave per o, 5 conditions per weight read)
//     block 1372: fn normalize -> fn global + loss_dis -> loss_out
__global__ void k_setup(const float* __restrict__ fc, const float* __restrict__ cw,
                        const float* __restrict__ cb, float* __restrict__ cm,
                        float* __restrict__ fn, float* __restrict__ loss_out) {
    __shared__ float sfc[C_*D_];
    int t = threadIdx.x;
    for (int i = t; i < C_*D_; i += 256) sfc[i] = fc[i];
    __syncthreads();
    int wave = t >> 6, lane = t & 63;

    if (blockIdx.x == 1372) {
        for (int c = wave; c < C_; c += 4) {
            float ss = 0.f;
            for (int d = lane; d < D_; d += 64) { float v = sfc[c*D_+d]; ss += v*v; }
            ss = wave_sum(ss);
            float inv = 1.f / fmaxf(sqrtf(ss), 1e-12f);
            for (int d = lane; d < D_; d += 64) sfc[c*D_+d] *= inv;
        }
        __syncthreads();
        for (int i = t; i < C_*D_; i += 256) fn[i] = sfc[i];
        if (wave == 0) {
            float acc = 0.f;
            for (int i = 0; i < C_; ++i)
                for (int j = i+1; j < C_; ++j) {
                    float p = 0.f;
                    for (int d = lane; d < D_; d += 64) p += sfc[i*D_+d]*sfc[j*D_+d];
                    p = wave_sum(p);
                    acc += fmaxf(p, 0.f);
                }
            if (lane == 0) *loss_out = acc * (1.f/10.f);
        }
        return;
    }

    int o = blockIdx.x*4 + wave;         // < 5488
    const float4* w4 = (const float4*)(cw + (size_t)o*D_);
    float4 wa = w4[lane], wb = w4[lane+64];
    float bias = cb[o];
    float keep = 0.f;
#pragma unroll
    for (int c = 0; c < C_; ++c) {
        const float4* f4 = (const float4*)(sfc + c*D_);
        float s = dot4(wa, f4[lane]) + dot4(wb, f4[lane+64]);
        s = wave_sum(s);
        if (lane == c) keep = s;
    }
    if (lane < C_) cm[lane*5488 + o] = keep + bias;
}

// K2: one wave per (b,l) prompt row: norm + 5 condition dots (independent chains)
// -> swl[b,c,l] = (fp[b,l]·fn[c]) / ||fp[b,l]||^2   (np never materialized)
__global__ void k_sim(const float* __restrict__ fp, const float* __restrict__ fn,
                      float* __restrict__ swl) {
    int bl = blockIdx.x; int b = bl / L_; int l = bl - b*L_;
    int lane = threadIdx.x;
    const float4* p = (const float4*)(fp + (size_t)bl*D_);
    float4 a = p[lane], a2 = p[lane+64];
    const float4* f0 = (const float4*)(fn + 0*D_);
    const float4* f1 = (const float4*)(fn + 1*D_);
    const float4* f2 = (const float4*)(fn + 2*D_);
    const float4* f3 = (const float4*)(fn + 3*D_);
    const float4* f4 = (const float4*)(fn + 4*D_);
    float ss = dot4(a,a) + dot4(a2,a2);
    float s0 = dot4(a, f0[lane]) + dot4(a2, f0[lane+64]);
    float s1 = dot4(a, f1[lane]) + dot4(a2, f1[lane+64]);
    float s2 = dot4(a, f2[lane]) + dot4(a2, f2[lane+64]);
    float s3 = dot4(a, f3[lane]) + dot4(a2, f3[lane+64]);
    float s4 = dot4(a, f4[lane]) + dot4(a2, f4[lane+64]);
    // six independent butterfly reductions — chains interleave
    ss = wave_sum(ss);
    s0 = wave_sum(s0); s1 = wave_sum(s1); s2 = wave_sum(s2);
    s3 = wave_sum(s3); s4 = wave_sum(s4);
    float inv = 1.f / fmaxf(sqrtf(ss), 1e-12f);
    float inv2 = inv*inv;
    float sel = (lane==0)?s0:((lane==1)?s1:((lane==2)?s2:((lane==3)?s3:s4)));
    if (lane < C_) swl[((size_t)(b*C_+lane))*L_ + l] = sel * inv2;
}

// K3: Q[b,c,d] = sum_l swl[b,c,l] * fp[b,l,d]
__global__ void k_Q(const float* __restrict__ fp, const float* __restrict__ swl,
                    float* __restrict__ Q) {
    __shared__ float sw[C_][80];
    int b = blockIdx.x;
    int t = threadIdx.x;                 // 256
    for (int i = t; i < C_*L_; i += 256) { int c = i/L_, l = i - c*L_; sw[c][l] = swl[((size_t)(b*C_+c))*L_ + l]; }
    __syncthreads();
    float2 a0={0,0}, a1={0,0}, a2={0,0}, a3={0,0}, a4={0,0};
    const float2* f2 = (const float2*)(fp + (size_t)b*L_*D_) + t;
    for (int l = 0; l < L_; ++l) {
        float2 v = f2[(size_t)l*256];
        float w0=sw[0][l], w1=sw[1][l], w2=sw[2][l], w3=sw[3][l], w4=sw[4][l];
        a0.x += w0*v.x; a0.y += w0*v.y;
        a1.x += w1*v.x; a1.y += w1*v.y;
        a2.x += w2*v.x; a2.y += w2*v.y;
        a3.x += w3*v.x; a3.y += w3*v.y;
        a4.x += w4*v.x; a4.y += w4*v.y;
    }
    ((float2*)(Q + (size_t)(b*C_+0)*D_))[t] = a0;
    ((float2*)(Q + (size_t)(b*C_+1)*D_))[t] = a1;
    ((float2*)(Q + (size_t)(b*C_+2)*D_))[t] = a2;
    ((float2*)(Q + (size_t)(b*C_+3)*D_))[t] = a3;
    ((float2*)(Q + (size_t)(b*C_+4)*D_))[t] = a4;
}

// K4: pw_raw[b,c,j] = (1/||tex[b,j]||) * dot(tex[b,j,:], Q[b,c,:])  [tex stream #1]
// 4 j per block (wave per j), Q staged in LDS.
__global__ void k_pw(const float* __restrict__ tex, const float* __restrict__ Q,
                     float* __restrict__ pw) {
    __shared__ float sq[C_*D_];
    int b = blockIdx.y, t = threadIdx.x;
    for (int i = t; i < C_*D_; i += 256) sq[i] = Q[(size_t)b*C_*D_ + i];
    __syncthreads();
    int wave = t >> 6, lane = t & 63;
    int j = blockIdx.x*4 + wave;
    if (j >= J_) return;
    const float4* t4 = (const float4*)(tex + ((size_t)b*J_ + j)*D_);
    float4 a = t4[lane], a2 = t4[lane+64];
    float ss = wave_sum(dot4(a,a) + dot4(a2,a2));
    float inv = 1.f / fmaxf(sqrtf(ss), 1e-12f);
    float keep = 0.f;
#pragma unroll
    for (int c = 0; c < C_; ++c) {
        const float4* q4 = (const float4*)(sq + c*D_);
        float s = dot4(a, q4[lane]) + dot4(a2, q4[lane+64]);
        s = wave_sum(s);
        if (lane == c) keep = s * inv;
    }
    if (lane < C_) pw[((size_t)(b*C_+lane))*J_ + j] = keep;
}

// K5: ftf partials with inline softmax  [tex stream #2]
__global__ void k_ftf(const float* __restrict__ tex, const float* __restrict__ pwraw,
                      float* __restrict__ part) {
    __shared__ float sw[C_][JC_];
    __shared__ float sms[C_][2];
    int chunk = blockIdx.x, b = blockIdx.y;
    int t = threadIdx.x;                 // 512
    int wave = t >> 6, lane = t & 63;
    if (wave < C_) {
        const float* row = pwraw + (size_t)(b*C_+wave)*J_;
        float m = -1e30f;
        for (int j = lane; j < J_; j += 64) m = fmaxf(m, row[j]);
        m = wave_max(m);
        float s = 0.f;
        for (int j = lane; j < J_; j += 64) s += expf(row[j] - m);
        s = wave_sum(s);
        if (lane == 0) { sms[wave][0] = m; sms[wave][1] = 1.f/s; }
    }
    __syncthreads();
    int j0 = chunk*JC_;
    int jn = min(JC_, J_ - j0);
    if (t < C_*JC_) {
        int c = t >> 6, jj = t & 63;
        sw[c][jj] = (jj < jn)
            ? expf(pwraw[((size_t)(b*C_+c))*J_ + j0 + jj] - sms[c][0]) * sms[c][1]
            : 0.f;
    }
    __syncthreads();
    float acc0=0.f, acc1=0.f, acc2=0.f, acc3=0.f, acc4=0.f;
    const float* tp = tex + ((size_t)b*J_ + j0)*D_ + t;
    for (int jj = 0; jj < jn; ++jj) {
        float v = tp[(size_t)jj*D_];
        acc0 += v*sw[0][jj]; acc1 += v*sw[1][jj]; acc2 += v*sw[2][jj];
        acc3 += v*sw[3][jj]; acc4 += v*sw[4][jj];
    }
    size_t base = (((size_t)chunk*B_ + b)*C_)*D_ + t;
    part[base               ] = acc0;
    part[base +   (size_t)D_] = acc1;
    part[base + 2*(size_t)D_] = acc2;
    part[base + 3*(size_t)D_] = acc3;
    part[base + 4*(size_t)D_] = acc4;
}

// K6: fused fq + TargetNet per (b,c) block. No shuffles anywhere.
__global__ void k_fq_target(const float* __restrict__ part, const float* __restrict__ eot,
                            const float* __restrict__ qw, const float* __restrict__ qb,
                            const float* __restrict__ g1w, const float* __restrict__ g2w,
                            const float* __restrict__ g3w, const float* __restrict__ g4w,
                            const float* __restrict__ fcb, float* __restrict__ out) {
    int bc = blockIdx.x; int b = bc / C_; int c = bc - b*C_;
    __shared__ float sf[D_];
    __shared__ float sa[224], sb[112];
    int t = threadIdx.x;                 // 256

    float s0 = 0.f, s1 = 0.f;
    for (int ch = 0; ch < NCH_; ++ch) {
        const float* p = part + ((size_t)ch*(B_*C_) + bc)*D_;
        s0 += p[t]; s1 += p[t+256];
    }
    sf[t]     = s0 * eot[b*D_ + t];
    sf[t+256] = s1 * eot[b*D_ + t + 256];
    __syncthreads();

    if (t < 224) {
        const float4* w4 = (const float4*)(qw + (size_t)t*D_);
        const float4* s4 = (const float4*)sf;
        float acc = 0.f;
#pragma unroll 4
        for (int i = 0; i < 128; ++i) acc += dot4(s4[i], w4[i]);
        sa[t] = acc + qb[t];
    }
    __syncthreads();

    if (t < 112) {
        const float* w = g1w + (size_t)c*25088 + t*224;
        float s = fcb[c*112 + t];
        for (int k = 0; k < 224; ++k) s += w[k]*sa[k];
        sb[t] = 1.f/(1.f+expf(-s));
    }
    __syncthreads();
    if (t < 56) {
        const float* w = g2w + (size_t)c*6272 + t*112;
        float s = fcb[560 + c*56 + t];
        for (int k = 0; k < 112; ++k) s += w[k]*sb[k];
        sa[t] = 1.f/(1.f+expf(-s));
    }
    __syncthreads();
    if (t < 28) {
        const float* w = g3w + (size_t)c*1568 + t*56;
        float s = fcb[840 + c*28 + t];
        for (int k = 0; k < 56; ++k) s += w[k]*sa[k];
        sb[t] = 1.f/(1.f+expf(-s));
    }
    __syncthreads();
    if (t < 14) {
        const float* w = g4w + (size_t)c*392 + t*28;
        float s = fcb[980 + c*14 + t];
        for (int k = 0; k < 28; ++k) s += w[k]*sb[k];
        sa[t] = 1.f/(1.f+expf(-s));
    }
    __syncthreads();
    if (t == 0) {
        float s = fcb[1120 + c];
        for (int p = 0; p < 14; ++p) s += sa[p]*fcb[1050 + c*14 + p];
        out[b*C_ + c] = s;
    }
}

// K7: convs + (on blockIdx.x==0) pooled + hypernet fc biases.
__global__ void k_conv(const float* __restrict__ cm,
                       const float* __restrict__ w1, const float* __restrict__ bb1,
                       const float* __restrict__ w2, const float* __restrict__ bb2,
                       const float* __restrict__ w3, const float* __restrict__ bb3,
                       const float* __restrict__ w4, const float* __restrict__ bb4,
                       float* __restrict__ o1, float* __restrict__ o2,
                       float* __restrict__ o3, float* __restrict__ o4,
                       const float* __restrict__ w1b, const float* __restrict__ b1b,
                       const float* __restrict__ w2b, const float* __restrict__ b2b,
                       const float* __restrict__ w3b, const float* __restrict__ b3b,
                       const float* __restrict__ w4b, const float* __restrict__ b4b,
                       const float* __restrict__ w5w, const float* __restrict__ b5w,
                       const float* __restrict__ w5b, const float* __restrict__ b5b,
                       float* __restrict__ fcb) {
    __shared__ float im[112*108];
    __shared__ float sp[112];
    int c = blockIdx.y;
    int t = threadIdx.x;
    for (int i = t; i < 112*108; i += 256) im[i] = 0.f;
    __syncthreads();
    const float* cmc = cm + c*5488;
    for (int i = t; i < 112*49; i += 256) {
        int ch = i / 49, yx = i - ch*49;
        int y = yx / 7, x = yx - y*7;
        im[ch*108 + (y+1)*12 + (x+1)] = cmc[i];
    }
    __syncthreads();

    int oy  = blockIdx.x*64 + (t >> 2);
    int chq = t & 3;
    if (oy < 4760) {
        int o_comb = oy / 7, y = oy - o_comb*7;
        const float* w; const float* bias; float* outp; int o;
        if      (o_comb < 512) { w=w1; bias=bb1; outp=o1 + (size_t)c*512*49; o=o_comb; }
        else if (o_comb < 640) { w=w2; bias=bb2; outp=o2 + (size_t)c*128*49; o=o_comb-512; }
        else if (o_comb < 672) { w=w3; bias=bb3; outp=o3 + (size_t)c*32*49;  o=o_comb-640; }
        else                   { w=w4; bias=bb4; outp=o4 + (size_t)c*8*49;   o=o_comb-672; }

        float ac0=0,ac1=0,ac2=0,ac3=0,ac4=0,ac5=0,ac6=0;
        const float* wbase = w + ((size_t)o*112 + chq*28)*9;
        const float* imc   = im + (chq*28)*108 + y*12;
#pragma unroll 2
        for (int ch = 0; ch < 28; ++ch) {
            const float* wk = wbase + ch*9;
            const float* ii = imc + ch*108;
            float w0=wk[0],w1_=wk[1],w2_=wk[2],w3_=wk[3],w4_=wk[4],w5_=wk[5],w6_=wk[6],w7_=wk[7],w8_=wk[8];
#pragma unroll
            for (int ky = 0; ky < 3; ++ky) {
                const float* row = ii + ky*12;
                float4 ra = *(const float4*)(row);
                float4 rb = *(const float4*)(row + 4);
                float  rc = row[8];
                float r0=ra.x,r1=ra.y,r2=ra.z,r3=ra.w,r4=rb.x,r5=rb.y,r6=rb.z,r7=rb.w,r8=rc;
                float wk0 = (ky==0)?w0:((ky==1)?w3_:w6_);
                float wk1 = (ky==0)?w1_:((ky==1)?w4_:w7_);
                float wk2 = (ky==0)?w2_:((ky==1)?w5_:w8_);
                ac0 += r0*wk0 + r1*wk1 + r2*wk2;
                ac1 += r1*wk0 + r2*wk1 + r3*wk2;
                ac2 += r2*wk0 + r3*wk1 + r4*wk2;
                ac3 += r3*wk0 + r4*wk1 + r5*wk2;
                ac4 += r4*wk0 + r5*wk1 + r6*wk2;
                ac5 += r5*wk0 + r6*wk1 + r7*wk2;
                ac6 += r6*wk0 + r7*wk1 + r8*wk2;
            }
        }
        ac0 += __shfl_xor(ac0,1,64); ac0 += __shfl_xor(ac0,2,64);
        ac1 += __shfl_xor(ac1,1,64); ac1 += __shfl_xor(ac1,2,64);
        ac2 += __shfl_xor(ac2,1,64); ac2 += __shfl_xor(ac2,2,64);
        ac3 += __shfl_xor(ac3,1,64); ac3 += __shfl_xor(ac3,2,64);
        ac4 += __shfl_xor(ac4,1,64); ac4 += __shfl_xor(ac4,2,64);
        ac5 += __shfl_xor(ac5,1,64); ac5 += __shfl_xor(ac5,2,64);
        ac6 += __shfl_xor(ac6,1,64); ac6 += __shfl_xor(ac6,2,64);
        if (chq == 0) {
            float bo = bias[o];
            float* dst = outp + o*49 + y*7;
            dst[0]=ac0+bo; dst[1]=ac1+bo; dst[2]=ac2+bo; dst[3]=ac3+bo;
            dst[4]=ac4+bo; dst[5]=ac5+bo; dst[6]=ac6+bo;
        }
    }

    if (blockIdx.x == 0) {
        if (t < 112) {
            const float* p = im + t*108;
            float s = 0.f;
            for (int k = 0; k < 108; ++k) s += p[k];
            sp[t] = s * (1.f/49.f);
        }
        __syncthreads();
        if (t < 225) {
            int rel = t;
            const float* w; const float* bb; int nout; int base;
            if      (rel < 112) {            w=w1b; bb=b1b; nout=112; base=0; }
            else if (rel < 168) { rel-=112;  w=w2b; bb=b2b; nout=56;  base=560; }
            else if (rel < 196) { rel-=168;  w=w3b; bb=b3b; nout=28;  base=840; }
            else if (rel < 210) { rel-=196;  w=w4b; bb=b4b; nout=14;  base=980; }
            else if (rel < 224) { rel-=210;  w=w5w; bb=b5w; nout=14;  base=1050; }
            else                { rel-=224;  w=w5b; bb=b5b; nout=1;   base=1120; }
            float s = bb[rel];
            const float* wr = w + rel*112;
            for (int i = 0; i < 112; ++i) s += sp[i]*wr[i];
            fcb[base + c*nout + rel] = s;
        }
    }
}

extern "C" void kernel_launch(void* const* d_in, const int* in_sizes, int n_in,
                              void* d_out, int out_size, void* d_ws, size_t ws_size,
                              hipStream_t stream) {
    (void)in_sizes; (void)n_in; (void)out_size; (void)ws_size;
    const float* tex   = (const float*)d_in[0];
    const float* fp    = (const float*)d_in[1];
    const float* eot   = (const float*)d_in[2];
    const float* fcond = (const float*)d_in[3];
    const float* qw    = (const float*)d_in[4];
    const float* qb    = (const float*)d_in[5];
    const float* cw    = (const float*)d_in[6];
    const float* cb    = (const float*)d_in[7];
    const float* w1c   = (const float*)d_in[8];  const float* b1c = (const float*)d_in[9];
    const float* w2c   = (const float*)d_in[10]; const float* b2c = (const float*)d_in[11];
    const float* w3c   = (const float*)d_in[12]; const float* b3c = (const float*)d_in[13];
    const float* w4c   = (const float*)d_in[14]; const float* b4c = (const float*)d_in[15];
    const float* f1bw  = (const float*)d_in[16]; const float* f1bb = (const float*)d_in[17];
    const float* f2bw  = (const float*)d_in[18]; const float* f2bb = (const float*)d_in[19];
    const float* f3bw  = (const float*)d_in[20]; const float* f3bb = (const float*)d_in[21];
    const float* f4bw  = (const float*)d_in[22]; const float* f4bb = (const float*)d_in[23];
    const float* f5ww  = (const float*)d_in[24]; const float* f5wb = (const float*)d_in[25];
    const float* f5bw  = (const float*)d_in[26]; const float* f5bb = (const float*)d_in[27];
    float* out = (float*)d_out;

    float* ws     = (float*)d_ws;
    float* Qb     = ws;                         // 81920
    float* pw     = Qb + 81920;                 // 189120
    float* part   = pw + 189120;                // NCH*81920
    float* cm     = part + (size_t)NCH_*81920;  // 27440
    float* g1w    = cm + 27440;                 // 125440
    float* g2w    = g1w + 125440;               // 31360
    float* g3w    = g2w + 31360;                // 7840
    float* g4w    = g3w + 7840;                 // 1960
    float* fcb    = g4w + 1960;                 // 1125
    float* fn     = fcb + 1125;                 // 2560
    float* swl    = fn + 2560;                  // 12320

    k_setup<<<1373, 256, 0, stream>>>(fcond, cw, cb, cm, fn, out + B_*C_);
    k_sim<<<B_*L_, 64, 0, stream>>>(fp, fn, swl);
    k_conv<<<dim3(75, C_), 256, 0, stream>>>(cm, w1c, b1c, w2c, b2c, w3c, b3c, w4c, b4c,
                                             g1w, g2w, g3w, g4w,
                                             f1bw, f1bb, f2bw, f2bb, f3bw, f3bb,
                                             f4bw, f4bb, f5ww, f5wb, f5bw, f5bb, fcb);
    k_Q<<<B_, 256, 0, stream>>>(fp, swl, Qb);
    k_pw<<<dim3(296, B_), 256, 0, stream>>>(tex, Qb, pw);
    k_ftf<<<dim3(NCH_, B_), 512, 0, stream>>>(tex, pw, part);
    k_fq_target<<<B_*C_, 256, 0, stream>>>(part, eot, qw, qb,
                                           g1w, g2w, g3w, g4w, fcb, out);
}